// Round 1
// baseline (4579.229 us; speedup 1.0000x reference)
//
#include <hip/hip_runtime.h>
#include <math.h>

#define N_ANCH 76725

struct TrunkArgs {
  const float* in[2][5];
  float* out[2][5];
  const float* w[2];
  const float* b[2];
};

struct OutArgs {
  const float* in[5];
  const float* w;
  const float* b;
  float* dst;
};

__device__ __forceinline__ int pick5(int l, int a, int b, int c, int d, int e) {
  int r = a;
  if (l == 1) r = b;
  if (l == 2) r = c;
  if (l == 3) r = d;
  if (l == 4) r = e;
  return r;
}

__device__ __forceinline__ void tile_to_level(int tile, int& lvl, int& t) {
  int l = 0;
  if (tile >= 100) l = 1;
  if (tile >= 125) l = 2;
  if (tile >= 134) l = 3;
  if (tile >= 138) l = 4;
  lvl = l;
  t = tile - pick5(l, 0, 100, 125, 134, 138);
}

// ---------------- trunk conv: 256->256, 3x3, SAME, ReLU ----------------
// block tile: 64 positions (8x8 spatial) x 64 output channels, BK=8.
// thread tile: 4 positions (one row) x 4 consecutive co.
__global__ __launch_bounds__(256) void conv_trunk(TrunkArgs args) {
  __shared__ float As[8][10][12];   // [ci][py][px], rows padded to 12 (16B aligned)
  __shared__ float Ws[8][9][68];    // [ci][tap][co], pad 68 breaks bank conflicts, keeps 16B align
  int lvl, t;
  tile_to_level(blockIdx.x, lvl, t);
  const int W = 80 >> lvl;
  const int HW = W * W;
  const int tX = (W + 7) >> 3;
  const int ty0 = (t / tX) * 8, tx0 = (t % tX) * 8;
  const int head = blockIdx.z;
  const int co0 = blockIdx.y << 6;
  const float* __restrict__ in = args.in[head][lvl];
  float* __restrict__ out = args.out[head][lvl];
  const float* __restrict__ wp = args.w[head];
  const int tid = threadIdx.x;
  const int cop = tid & 15, posp = tid >> 4;
  const int py = posp >> 1, px = (posp & 1) << 2;
  const int co_sub = cop << 2;
  float acc[4][4] = {};

  for (int ci0 = 0; ci0 < 256; ci0 += 8) {
    __syncthreads();
    // stage input patch: 8 ci x 10x10 (halo 1, zero pad at borders)
    for (int e = tid; e < 800; e += 256) {
      int ci = e / 100;
      int rem = e - ci * 100;
      int yy = rem / 10;
      int xx = rem - yy * 10;
      int gy = ty0 + yy - 1, gx = tx0 + xx - 1;
      float v = 0.f;
      if ((unsigned)gy < (unsigned)W && (unsigned)gx < (unsigned)W)
        v = in[(ci0 + ci) * HW + gy * W + gx];
      As[ci][yy][xx] = v;
    }
    // stage weights: 64 co x 8 ci x 9 taps (coalesced over [ci][tap] runs of 72)
    const float* wb = wp + (size_t)co0 * 2304 + (size_t)ci0 * 9;
    for (int e = tid; e < 4608; e += 256) {
      int tap = e % 9;
      int ci = (e / 9) & 7;
      int co = e / 72;
      Ws[ci][tap][co] = wb[co * 2304 + ci * 9 + tap];
    }
    __syncthreads();
    #pragma unroll 2
    for (int ci = 0; ci < 8; ci++) {
      #pragma unroll
      for (int ty = 0; ty < 3; ty++) {
        const float* ar = &As[ci][py + ty][px];
        float4 av = *(const float4*)ar;         // aligned: row stride 48B, px in {0,4}
        float2 av2 = *(const float2*)(ar + 4);
        float a[6] = {av.x, av.y, av.z, av.w, av2.x, av2.y};
        #pragma unroll
        for (int tx = 0; tx < 3; tx++) {
          float4 wv = *(const float4*)&Ws[ci][ty * 3 + tx][co_sub];
          #pragma unroll
          for (int p = 0; p < 4; p++) {
            acc[p][0] = fmaf(a[tx + p], wv.x, acc[p][0]);
            acc[p][1] = fmaf(a[tx + p], wv.y, acc[p][1]);
            acc[p][2] = fmaf(a[tx + p], wv.z, acc[p][2]);
            acc[p][3] = fmaf(a[tx + p], wv.w, acc[p][3]);
          }
        }
      }
    }
  }
  const float4 bias = *(const float4*)&args.b[head][co0 + co_sub];
  const int oy = ty0 + py;
  if (oy < W) {
    #pragma unroll
    for (int p = 0; p < 4; p++) {
      int ox = tx0 + px + p;
      if (ox < W) {
        int base = oy * W + ox;
        out[(co0 + co_sub + 0) * HW + base] = fmaxf(acc[p][0] + bias.x, 0.f);
        out[(co0 + co_sub + 1) * HW + base] = fmaxf(acc[p][1] + bias.y, 0.f);
        out[(co0 + co_sub + 2) * HW + base] = fmaxf(acc[p][2] + bias.z, 0.f);
        out[(co0 + co_sub + 3) * HW + base] = fmaxf(acc[p][3] + bias.w, 0.f);
      }
    }
  }
}

// ---------------- output conv: 256 -> CO (9 cls / 36 reg), NHWC scatter ----------------
template <int CO, bool SIG>
__global__ __launch_bounds__(256) void conv_out_k(OutArgs args) {
  __shared__ float As[8][10][12];
  __shared__ float Wo[8][9][CO];
  int lvl, t;
  tile_to_level(blockIdx.x, lvl, t);
  const int W = 80 >> lvl;
  const int HW = W * W;
  const int tX = (W + 7) >> 3;
  const int ty0 = (t / tX) * 8, tx0 = (t % tX) * 8;
  const float* __restrict__ in = args.in[lvl];
  const int tid = threadIdx.x;
  const int pos = tid & 63;
  const int y = pos >> 3, x = pos & 7;
  const int cset = tid >> 6;
  constexpr int NJ = (CO + 3) / 4;
  float acc[NJ] = {};

  for (int ci0 = 0; ci0 < 256; ci0 += 8) {
    __syncthreads();
    for (int e = tid; e < 800; e += 256) {
      int ci = e / 100;
      int rem = e - ci * 100;
      int yy = rem / 10;
      int xx = rem - yy * 10;
      int gy = ty0 + yy - 1, gx = tx0 + xx - 1;
      float v = 0.f;
      if ((unsigned)gy < (unsigned)W && (unsigned)gx < (unsigned)W)
        v = in[(ci0 + ci) * HW + gy * W + gx];
      As[ci][yy][xx] = v;
    }
    for (int e = tid; e < CO * 72; e += 256) {
      int tap = e % 9;
      int ci = (e / 9) & 7;
      int co = e / 72;
      Wo[ci][tap][co] = args.w[co * 2304 + (ci0 + ci) * 9 + tap];
    }
    __syncthreads();
    #pragma unroll 2
    for (int ci = 0; ci < 8; ci++) {
      #pragma unroll
      for (int ty = 0; ty < 3; ty++) {
        float a[3];
        a[0] = As[ci][y + ty][x + 0];
        a[1] = As[ci][y + ty][x + 1];
        a[2] = As[ci][y + ty][x + 2];
        #pragma unroll
        for (int tx = 0; tx < 3; tx++) {
          const float* wr = &Wo[ci][ty * 3 + tx][0];
          #pragma unroll
          for (int j = 0; j < NJ; j++) {
            int co = cset + 4 * j;
            if (co < CO) acc[j] = fmaf(a[tx], wr[co], acc[j]);
          }
        }
      }
    }
  }
  const int oy = ty0 + y, ox = tx0 + x;
  if (oy < W && ox < W) {
    const int cell = oy * W + ox;
    const int aoff = pick5(lvl, 0, 57600, 72000, 75600, 76500) * (CO / 9);
    #pragma unroll
    for (int j = 0; j < NJ; j++) {
      int co = cset + 4 * j;
      if (co < CO) {
        float v = acc[j] + args.b[co];
        if (SIG) v = 1.f / (1.f + expf(-v));
        args.dst[aoff + cell * CO + co] = v;
      }
    }
  }
}

// ---------------- init / decode / NMS ----------------
__global__ void init_k(int* cnt) {
  if (threadIdx.x == 0 && blockIdx.x == 0) *cnt = 0;
}

__global__ __launch_bounds__(256) void decode_k(const float* __restrict__ scores,
                                                const float* __restrict__ regs,
                                                float* cand_s, float4* cand_b,
                                                int* cand_n, int* cnt) {
  int n = blockIdx.x * 256 + threadIdx.x;
  if (n >= N_ANCH) return;
  int lvl = 0;
  if (n >= 57600) lvl = 1;
  if (n >= 72000) lvl = 2;
  if (n >= 75600) lvl = 3;
  if (n >= 76500) lvl = 4;
  const int aoff = pick5(lvl, 0, 57600, 72000, 75600, 76500);
  const int W = 80 >> lvl;
  int r = n - aoff;
  int a = r % 9;
  int cell = r / 9;
  int x = cell % W, y = cell / W;
  // anchors in double, single rounding to f32 (matches numpy build_anchors)
  double stride = (double)(8 << lvl);
  double base = (double)(32 << lvl);
  int si = a % 3, ri = a / 3;
  double s = (si == 0) ? 1.0 : (si == 1) ? 1.2599210498948731648 : 1.5874010519681994748;
  double ratio = (ri == 0) ? 0.5 : (ri == 1) ? 1.0 : 2.0;
  double ws0 = base * s;
  double area = ws0 * ws0;
  double w = sqrt(area / ratio);
  double h = w * ratio;
  double cx = ((double)x + 0.5) * stride;
  double cy = ((double)y + 0.5) * stride;
  float ax1 = (float)(cx - 0.5 * w);
  float ay1 = (float)(cy - 0.5 * h);
  float ax2 = (float)(cx + (w - 0.5 * w));
  float ay2 = (float)(cy + (h - 0.5 * h));
  float4 rg = ((const float4*)regs)[n];
  float aw = ax2 - ax1, ah = ay2 - ay1;
  float acx = ax1 + 0.5f * aw, acy = ay1 + 0.5f * ah;
  float pcx = acx + rg.x * 0.1f * aw;
  float pcy = acy + rg.y * 0.1f * ah;
  float pw = expf(rg.z * 0.2f) * aw;
  float ph = expf(rg.w * 0.2f) * ah;
  float x1 = pcx - 0.5f * pw, y1 = pcy - 0.5f * ph;
  float x2 = pcx + 0.5f * pw, y2 = pcy + 0.5f * ph;
  x1 = fminf(fmaxf(x1, 0.f), 640.f);
  y1 = fminf(fmaxf(y1, 0.f), 640.f);
  x2 = fminf(fmaxf(x2, 0.f), 640.f);
  y2 = fminf(fmaxf(y2, 0.f), 640.f);
  float sc = scores[n];
  if (sc > 0.05f) {
    int p = atomicAdd(cnt, 1);
    cand_s[p] = sc;
    cand_b[p] = make_float4(x1, y1, x2, y2);
    cand_n[p] = n;
  }
}

// greedy NMS, one block. Each iteration fuses suppression-by-previous-pick with
// the argmax for the next pick (single pass over candidates). First-index
// tie-break (on original anchor id) mirrors jnp.argmax.
__global__ __launch_bounds__(1024) void nms_k(float* cs, const float4* __restrict__ cb,
                                              const int* __restrict__ cn,
                                              const int* __restrict__ cnt,
                                              float* __restrict__ out) {
  __shared__ float rs[16];
  __shared__ int rn[16];
  __shared__ int rj[16];
  __shared__ float sS;
  __shared__ int sJ;
  const int tid = threadIdx.x;
  const int m = min(*cnt, N_ANCH);
  float selS = -INFINITY;
  int selJ = 0;
  float4 selB = make_float4(0.f, 0.f, 0.f, 0.f);
  float selA = 0.f;

  for (int it = 0; it <= 300; it++) {
    if (it > 0 && tid == 0) {
      int i = it - 1;
      bool keep = selS != -INFINITY;
      out[i] = keep ? selS : 0.f;
      out[300 + i] = keep ? 0.f : -1.f;   // label 0 if kept else -1
      float4 b = keep ? selB : make_float4(0.f, 0.f, 0.f, 0.f);
      out[600 + 4 * i + 0] = b.x;
      out[600 + 4 * i + 1] = b.y;
      out[600 + 4 * i + 2] = b.z;
      out[600 + 4 * i + 3] = b.w;
    }
    if (it == 300) break;
    const bool sup = it > 0;
    float bs = -INFINITY;
    int bn = 0x7fffffff;
    int bj = 0;
    for (int j = tid; j < m; j += 1024) {
      float s = cs[j];
      if (s == -INFINITY) continue;
      if (sup) {
        float4 b = cb[j];
        float xx1 = fmaxf(selB.x, b.x), yy1 = fmaxf(selB.y, b.y);
        float xx2 = fminf(selB.z, b.z), yy2 = fminf(selB.w, b.w);
        float inter = fmaxf(xx2 - xx1, 0.f) * fmaxf(yy2 - yy1, 0.f);
        float ar = (b.z - b.x) * (b.w - b.y);
        float iou = inter / (ar + selA - inter + 1e-8f);
        if (iou > 0.5f) {
          cs[j] = -INFINITY;
          continue;
        }
      }
      int n = cn[j];
      if (s > bs || (s == bs && n < bn)) { bs = s; bn = n; bj = j; }
    }
    #pragma unroll
    for (int off = 32; off; off >>= 1) {
      float os = __shfl_down(bs, off);
      int on = __shfl_down(bn, off);
      int oj = __shfl_down(bj, off);
      if (os > bs || (os == bs && on < bn)) { bs = os; bn = on; bj = oj; }
    }
    if ((tid & 63) == 0) {
      int wv = tid >> 6;
      rs[wv] = bs; rn[wv] = bn; rj[wv] = bj;
    }
    __syncthreads();
    if (tid == 0) {
      for (int k = 1; k < 16; k++)
        if (rs[k] > bs || (rs[k] == bs && rn[k] < bn)) { bs = rs[k]; bn = rn[k]; bj = rj[k]; }
      sS = bs; sJ = bj;
    }
    __syncthreads();
    selS = sS;
    selJ = sJ;
    if (selS != -INFINITY) selB = cb[selJ];
    else selB = make_float4(0.f, 0.f, 0.f, 0.f);
    selA = (selB.z - selB.x) * (selB.w - selB.y);
  }
}

// ---------------- host ----------------
extern "C" void kernel_launch(void* const* d_in, const int* in_sizes, int n_in,
                              void* d_out, int out_size, void* d_ws, size_t ws_size,
                              hipStream_t stream) {
  (void)in_sizes; (void)n_in; (void)out_size; (void)ws_size;
  const float* feats[5];
  for (int l = 0; l < 5; l++) feats[l] = (const float*)d_in[1 + l];
  const float* cls_w = (const float*)d_in[6];
  const float* cls_b = (const float*)d_in[7];
  const float* cls_ow = (const float*)d_in[8];
  const float* cls_ob = (const float*)d_in[9];
  const float* reg_w = (const float*)d_in[10];
  const float* reg_b = (const float*)d_in[11];
  const float* reg_ow = (const float*)d_in[12];
  const float* reg_ob = (const float*)d_in[13];

  static const int AOFF[5] = {0, 1638400, 2048000, 2150400, 2176000}; // 256*cumHW
  const size_t ACT = 2182400;  // 256*8525 floats per head

  float* ws = (float*)d_ws;
  float* bufA = ws;                       // 2*ACT
  float* bufB = bufA + 2 * ACT;           // 2*ACT
  float* scores = bufB + 2 * ACT;         // 76736 (padded)
  float* regs = scores + 76736;           // 306912 (padded)
  float* cand_s = regs + 306912;          // 76736
  float* cand_b = cand_s + 76736;         // 306944
  int* cand_n = (int*)(cand_b + 306944);  // 76736 ints
  int* cnt = cand_n + 76736;

  float* bufs[2] = {bufA, bufB};
  TrunkArgs ta;
  for (int layer = 0; layer < 4; layer++) {
    for (int h = 0; h < 2; h++) {
      ta.w[h] = (h ? reg_w : cls_w) + (size_t)layer * 589824;
      ta.b[h] = (h ? reg_b : cls_b) + layer * 256;
      for (int l = 0; l < 5; l++) {
        ta.out[h][l] = bufs[layer & 1] + h * ACT + AOFF[l];
        ta.in[h][l] = (layer == 0) ? feats[l] : (const float*)(bufs[(layer - 1) & 1] + h * ACT + AOFF[l]);
      }
    }
    conv_trunk<<<dim3(139, 4, 2), dim3(256), 0, stream>>>(ta);
  }

  OutArgs oc, og;
  for (int l = 0; l < 5; l++) {
    oc.in[l] = bufB + 0 * ACT + AOFF[l];
    og.in[l] = bufB + 1 * ACT + AOFF[l];
  }
  oc.w = cls_ow; oc.b = cls_ob; oc.dst = scores;
  og.w = reg_ow; og.b = reg_ob; og.dst = regs;
  conv_out_k<9, true><<<dim3(139), dim3(256), 0, stream>>>(oc);
  conv_out_k<36, false><<<dim3(139), dim3(256), 0, stream>>>(og);

  init_k<<<1, 64, 0, stream>>>(cnt);
  decode_k<<<dim3((N_ANCH + 255) / 256), dim3(256), 0, stream>>>(scores, regs, cand_s,
                                                                 (float4*)cand_b, cand_n, cnt);
  nms_k<<<1, 1024, 0, stream>>>(cand_s, (const float4*)cand_b, cand_n, cnt, (float*)d_out);
}